// Round 1
// baseline (2020.081 us; speedup 1.0000x reference)
//
#include <hip/hip_runtime.h>

#define IN_CH 128
#define HIDC  128
#define NREL  8

// ---------------------------------------------------------------------------
// Scatter-aggregate: one wave (64 lanes) per edge; each lane handles 2 channels.
// agg layout: [N, rel_cnt*128]  (node-major so GEMM K-dim is contiguous)
// cnt layout: [N, 8] (global relation index)
// ---------------------------------------------------------------------------
__global__ __launch_bounds__(256) void scatter_kernel(
    const float* __restrict__ x,
    const int* __restrict__ src,
    const int* __restrict__ dst,
    const int* __restrict__ et,
    float* __restrict__ agg,
    float* __restrict__ cnt,
    int E, int rel_base, int rel_cnt)
{
    int gtid = blockIdx.x * blockDim.x + threadIdx.x;
    int wave = gtid >> 6;
    int lane = threadIdx.x & 63;
    int nw   = (gridDim.x * blockDim.x) >> 6;
    int stride_a = rel_cnt * 128;
    for (int e = wave; e < E; e += nw) {
        int t = et[e] - rel_base;
        if ((unsigned)t < (unsigned)rel_cnt) {
            int s = src[e];
            int d = dst[e];
            float2 xv = *(const float2*)(x + (size_t)s * IN_CH + lane * 2);
            float* ap = agg + (size_t)d * stride_a + t * 128 + lane * 2;
            atomicAdd(ap,     xv.x);
            atomicAdd(ap + 1, xv.y);
            if (lane == 0) atomicAdd(cnt + (size_t)d * NREL + rel_base + t, 1.0f);
        }
    }
}

// ---------------------------------------------------------------------------
// fp32 tiled GEMM: out[n][h] (+)= A[n][k] * B[k][h], K multiple of 32,
// HID fixed 128. Tile: 64 nodes x 128 hid per 256-thread block.
// If cnt != null: A is an aggregation buffer, scale row-chunks by 1/max(cnt,1)
// (relation = rel_base + k/128).
// flags: bit0 = init with bias (write out), else accumulate into out (RMW)
//        bit1 = apply ReLU at the end
// ---------------------------------------------------------------------------
#define TM 64
__global__ __launch_bounds__(256) void gemm_kernel(
    const float* __restrict__ A,
    const float* __restrict__ B,
    const float* __restrict__ cnt,
    const float* __restrict__ bias,
    float* __restrict__ out,
    int N, int K, int rel_base, int flags)
{
    __shared__ float As[32][TM + 1];
    __shared__ float Bs[32][HIDC];

    int tid = threadIdx.x;
    int tn  = tid & 31;   // hid group: columns tn*4 .. tn*4+3
    int tm  = tid >> 5;   // node group: rows tm*8 .. tm*8+7
    int n0  = blockIdx.x * TM;

    float4 acc[8];
#pragma unroll
    for (int i = 0; i < 8; i++) acc[i] = float4{0.f, 0.f, 0.f, 0.f};

    for (int kc = 0; kc < K; kc += 32) {
        // --- stage A tile (64 x 32), transposed into As[k][n] ---
#pragma unroll
        for (int i = 0; i < 2; i++) {
            int idx = tid + i * 256;       // 0..511 float4 slots
            int n   = idx >> 3;            // 0..63
            int kk  = (idx & 7) * 4;       // 0..28
            int gn  = n0 + n;
            float4 v = float4{0.f, 0.f, 0.f, 0.f};
            if (gn < N) {
                v = *(const float4*)(A + (size_t)gn * K + kc + kk);
                if (cnt) {
                    int r = rel_base + ((kc + kk) >> 7);
                    float c = cnt[(size_t)gn * NREL + r];
                    float inv = 1.0f / fmaxf(c, 1.0f);
                    v.x *= inv; v.y *= inv; v.z *= inv; v.w *= inv;
                }
            }
            As[kk + 0][n] = v.x;
            As[kk + 1][n] = v.y;
            As[kk + 2][n] = v.z;
            As[kk + 3][n] = v.w;
        }
        // --- stage B tile (32 x 128) ---
#pragma unroll
        for (int i = 0; i < 4; i++) {
            int idx = tid + i * 256;       // 0..1023 float4 slots
            int kk  = idx >> 5;            // 0..31
            int h4  = (idx & 31) * 4;
            *(float4*)&Bs[kk][h4] = *(const float4*)(B + (size_t)(kc + kk) * HIDC + h4);
        }
        __syncthreads();

#pragma unroll
        for (int kk = 0; kk < 32; kk++) {
            float4 b = *(float4*)&Bs[kk][tn * 4];
#pragma unroll
            for (int i = 0; i < 8; i++) {
                float a = As[kk][tm * 8 + i];
                acc[i].x += a * b.x;
                acc[i].y += a * b.y;
                acc[i].z += a * b.z;
                acc[i].w += a * b.w;
            }
        }
        __syncthreads();
    }

    // --- epilogue ---
#pragma unroll
    for (int i = 0; i < 8; i++) {
        int gn = n0 + tm * 8 + i;
        if (gn >= N) continue;
        float* op = out + (size_t)gn * HIDC + tn * 4;
        float4 o;
        if (flags & 1) {
            o.x = bias[tn * 4 + 0];
            o.y = bias[tn * 4 + 1];
            o.z = bias[tn * 4 + 2];
            o.w = bias[tn * 4 + 3];
        } else {
            o = *(float4*)op;
        }
        o.x += acc[i].x; o.y += acc[i].y; o.z += acc[i].z; o.w += acc[i].w;
        if (flags & 2) {
            o.x = fmaxf(o.x, 0.f);
            o.y = fmaxf(o.y, 0.f);
            o.z = fmaxf(o.z, 0.f);
            o.w = fmaxf(o.w, 0.f);
        }
        *(float4*)op = o;
    }
}

extern "C" void kernel_launch(void* const* d_in, const int* in_sizes, int n_in,
                              void* d_out, int out_size, void* d_ws, size_t ws_size,
                              hipStream_t stream)
{
    const float* x    = (const float*)d_in[0];
    const int*   ei   = (const int*)d_in[1];
    const int*   et   = (const int*)d_in[2];
    const float* W    = (const float*)d_in[3];
    const float* root = (const float*)d_in[4];
    const float* bias = (const float*)d_in[5];
    float*       out  = (float*)d_out;

    int N = in_sizes[0] / IN_CH;
    int E = in_sizes[2];
    const int* src = ei;
    const int* dst = ei + E;

    // workspace: cnt [N,8] then agg [N, rc*128]
    float* cnt = (float*)d_ws;
    float* agg = cnt + (size_t)N * NREL;
    size_t ws_floats  = ws_size / 4;
    size_t cnt_floats = (size_t)N * NREL;
    size_t agg_floats = (ws_floats > cnt_floats) ? (ws_floats - cnt_floats) : 0;
    int rc = (int)(agg_floats / ((size_t)N * 128));
    if (rc > NREL) rc = NREL;
    if (rc < 1)    rc = 1;   // assume ws_size >= ~55 MB

    int gemm_grid = (N + TM - 1) / TM;

    // root/self-loop term: out = x @ root + bias
    gemm_kernel<<<gemm_grid, 256, 0, stream>>>(x, root, nullptr, bias, out,
                                               N, IN_CH, 0, /*flags=*/1);

    for (int base = 0; base < NREL; base += rc) {
        int c = NREL - base < rc ? NREL - base : rc;
        size_t zero_bytes = (cnt_floats + (size_t)N * c * 128) * sizeof(float);
        hipMemsetAsync(d_ws, 0, zero_bytes, stream);
        scatter_kernel<<<1024, 256, 0, stream>>>(x, src, dst, et, agg, cnt,
                                                 E, base, c);
        int flags = (base + c >= NREL) ? 2 : 0;
        gemm_kernel<<<gemm_grid, 256, 0, stream>>>(agg, W + (size_t)base * IN_CH * HIDC,
                                                   cnt, nullptr, out,
                                                   N, c * 128, base, flags);
    }
}

// Round 2
// 657.937 us; speedup vs baseline: 3.0703x; 3.0703x over previous
//
#include <hip/hip_runtime.h>

#define NREL 8
#define CH   128                 // IN_CH == HID == 128
#define KAGG (NREL * CH)         // 1024
#define KTOT (KAGG + CH)         // 1152 (agg relations + root/x)

#define SCAN_ITEMS   16
#define SCAN_THREADS 256
#define SCAN_CHUNK   (SCAN_ITEMS * SCAN_THREADS)   // 4096
#define SCAN_SHIFT   12                            // log2(SCAN_CHUNK)

typedef short short8 __attribute__((ext_vector_type(8)));
typedef float f32x4  __attribute__((ext_vector_type(4)));

__device__ __forceinline__ unsigned short f2bf(float f) {
    union { float f; unsigned u; } v; v.f = f;
    // round-to-nearest-even truncation to bf16
    return (unsigned short)((v.u + 0x7FFFu + ((v.u >> 16) & 1u)) >> 16);
}

// ---------------------------------------------------------------------------
// 1. histogram over segments seg = dst*8 + rel
// ---------------------------------------------------------------------------
__global__ __launch_bounds__(256) void hist_kernel(
    const int* __restrict__ dst, const int* __restrict__ et,
    int* __restrict__ hist, int E)
{
    int stride = gridDim.x * blockDim.x;
    for (int e = blockIdx.x * blockDim.x + threadIdx.x; e < E; e += stride)
        atomicAdd(&hist[dst[e] * NREL + et[e]], 1);
}

// ---------------------------------------------------------------------------
// 2a. per-block exclusive scan (4096 items / block) + block totals
// ---------------------------------------------------------------------------
__global__ __launch_bounds__(SCAN_THREADS) void scan1_kernel(
    const int* __restrict__ hist, int* __restrict__ offs,
    int* __restrict__ partials, int S)
{
    __shared__ int lds[SCAN_THREADS];
    int t = threadIdx.x;
    int base = blockIdx.x * SCAN_CHUNK + t * SCAN_ITEMS;

    int v[SCAN_ITEMS];
    int s = 0;
#pragma unroll
    for (int j = 0; j < SCAN_ITEMS; j++) {
        int idx = base + j;
        int h = (idx < S) ? hist[idx] : 0;
        v[j] = s;            // exclusive prefix within thread
        s += h;
    }
    int run = s;
    lds[t] = run;
    __syncthreads();
    for (int off = 1; off < SCAN_THREADS; off <<= 1) {
        int y = (t >= off) ? lds[t - off] : 0;
        __syncthreads();
        run += y;
        lds[t] = run;
        __syncthreads();
    }
    int tb = run - s;        // exclusive thread base
    if (t == SCAN_THREADS - 1) partials[blockIdx.x] = run;   // block total
#pragma unroll
    for (int j = 0; j < SCAN_ITEMS; j++) {
        int idx = base + j;
        if (idx < S) offs[idx] = tb + v[j];
    }
}

// ---------------------------------------------------------------------------
// 2b. single-block exclusive scan of block totals (NB <= 256)
// ---------------------------------------------------------------------------
__global__ __launch_bounds__(SCAN_THREADS) void scan2_kernel(
    int* __restrict__ partials, int NB)
{
    __shared__ int lds[SCAN_THREADS];
    int t = threadIdx.x;
    int s = (t < NB) ? partials[t] : 0;
    int run = s;
    lds[t] = run;
    __syncthreads();
    for (int off = 1; off < SCAN_THREADS; off <<= 1) {
        int y = (t >= off) ? lds[t - off] : 0;
        __syncthreads();
        run += y;
        lds[t] = run;
        __syncthreads();
    }
    if (t < NB) partials[t] = run - s;   // exclusive block offsets
}

// ---------------------------------------------------------------------------
// 3. fill permutation: perm[slot] = src[e], slots grouped by segment
// ---------------------------------------------------------------------------
__global__ __launch_bounds__(256) void fill_kernel(
    const int* __restrict__ src, const int* __restrict__ dst,
    const int* __restrict__ et, const int* __restrict__ offs,
    const int* __restrict__ partials, int* __restrict__ cursor,
    int* __restrict__ perm, int E)
{
    int stride = gridDim.x * blockDim.x;
    for (int e = blockIdx.x * blockDim.x + threadIdx.x; e < E; e += stride) {
        int seg = dst[e] * NREL + et[e];
        int pos = offs[seg] + partials[seg >> SCAN_SHIFT] + atomicAdd(&cursor[seg], 1);
        perm[pos] = src[e];
    }
}

// ---------------------------------------------------------------------------
// 4. segment gather-aggregate: one wave per (node, rel) segment.
//    fp32 accumulate, divide by count, write bf16 mean. No atomics.
//    agg layout: [N][1024] bf16  (k = rel*128 + ch)
// ---------------------------------------------------------------------------
__global__ __launch_bounds__(256) void agg_kernel(
    const float* __restrict__ x, const int* __restrict__ perm,
    const int* __restrict__ offs, const int* __restrict__ partials,
    const int* __restrict__ hist, unsigned short* __restrict__ agg, int S)
{
    int wid  = threadIdx.x >> 6;
    int lane = threadIdx.x & 63;
    int seg  = blockIdx.x * 4 + wid;
    if (seg >= S) return;

    int beg = offs[seg] + partials[seg >> SCAN_SHIFT];
    int cnt = hist[seg];

    float ax = 0.f, ay = 0.f;
    for (int e = beg; e < beg + cnt; ++e) {
        int s = perm[e];
        float2 xv = *(const float2*)(x + (size_t)s * CH + lane * 2);
        ax += xv.x; ay += xv.y;
    }
    float inv = 1.0f / fmaxf((float)cnt, 1.0f);
    ushort2 o;
    o.x = f2bf(ax * inv);
    o.y = f2bf(ay * inv);
    int n = seg >> 3, r = seg & 7;
    *(ushort2*)(agg + (size_t)n * KAGG + r * CH + lane * 2) = o;
}

// ---------------------------------------------------------------------------
// 5. bf16 MFMA GEMM: out = relu([agg | bf16(x)] @ [W | root] + bias)
//    A: [N][1152]  (agg bf16 for k<1024, x cvt on the fly for k>=1024)
//    B: [1152][128] fp32 (W then root), cvt to bf16 during staging
//    block tile 128x128, 4 waves (2x2), 16x16x32 MFMA, BK=32
// ---------------------------------------------------------------------------
#define BM 128
#define BK 32
#define LDP 40    // padded k-stride (elements): 80 B -> 2-way max conflict

__global__ __launch_bounds__(256) void gemm_kernel(
    const unsigned short* __restrict__ agg,
    const float* __restrict__ x,
    const float* __restrict__ W,      // [1024][128]
    const float* __restrict__ root,   // [128][128]
    const float* __restrict__ bias,
    float* __restrict__ out, int N)
{
    __shared__ unsigned short As[BM][LDP];   // [row][k]
    __shared__ unsigned short Bs[CH][LDP];   // [col][k]

    int tid  = threadIdx.x;
    int n0   = blockIdx.x * BM;
    int wid  = tid >> 6;
    int lane = tid & 63;
    int wm   = wid >> 1;        // wave row block (0..1), 64 rows
    int wn   = wid & 1;         // wave col block (0..1), 64 cols
    int r15  = lane & 15;
    int kg   = lane >> 4;       // 0..3
    int k8   = kg * 8;

    f32x4 acc[4][4];
#pragma unroll
    for (int i = 0; i < 4; i++)
#pragma unroll
        for (int j = 0; j < 4; j++)
            acc[i][j] = f32x4{0.f, 0.f, 0.f, 0.f};

    for (int kc = 0; kc < KTOT; kc += BK) {
        // ---- stage A: 128 rows x 32 k (bf16), 512 x 16B chunks ----
#pragma unroll
        for (int i = 0; i < 2; i++) {
            int idx = tid + i * 256;
            int row = idx >> 2;
            int kq  = (idx & 3) * 8;
            int gn  = n0 + row;
            int gk  = kc + kq;
            uint4 v = uint4{0u, 0u, 0u, 0u};
            if (gn < N) {
                if (gk < KAGG) {
                    v = *(const uint4*)(agg + (size_t)gn * KAGG + gk);
                } else {
                    const float* xp = x + (size_t)gn * CH + (gk - KAGG);
                    float4 f0 = *(const float4*)xp;
                    float4 f1 = *(const float4*)(xp + 4);
                    v.x = f2bf(f0.x) | ((unsigned)f2bf(f0.y) << 16);
                    v.y = f2bf(f0.z) | ((unsigned)f2bf(f0.w) << 16);
                    v.z = f2bf(f1.x) | ((unsigned)f2bf(f1.y) << 16);
                    v.w = f2bf(f1.z) | ((unsigned)f2bf(f1.w) << 16);
                }
            }
            *(uint4*)&As[row][kq] = v;
        }
        // ---- stage B: 32 k x 128 col, transposed to Bs[col][k] ----
#pragma unroll
        for (int i = 0; i < 4; i++) {
            int lin = tid + i * 256;
            int k   = lin >> 5;
            int h0  = (lin & 31) * 4;
            int gk  = kc + k;
            const float* bp = (gk < KAGG)
                ? (W + (size_t)gk * CH + h0)
                : (root + (size_t)(gk - KAGG) * CH + h0);
            float4 f = *(const float4*)bp;
            Bs[h0 + 0][k] = f2bf(f.x);
            Bs[h0 + 1][k] = f2bf(f.y);
            Bs[h0 + 2][k] = f2bf(f.z);
            Bs[h0 + 3][k] = f2bf(f.w);
        }
        __syncthreads();

        // ---- MFMA: both A and B use k = kg*8 + j (same mapping -> any
        //      k-permutation cancels in the dot product) ----
        short8 a[4], b[4];
#pragma unroll
        for (int mr = 0; mr < 4; mr++)
            a[mr] = *(const short8*)&As[wm * 64 + mr * 16 + r15][k8];
#pragma unroll
        for (int nc = 0; nc < 4; nc++)
            b[nc] = *(const short8*)&Bs[wn * 64 + nc * 16 + r15][k8];
#pragma unroll
        for (int mr = 0; mr < 4; mr++)
#pragma unroll
            for (int nc = 0; nc < 4; nc++)
                acc[mr][nc] = __builtin_amdgcn_mfma_f32_16x16x32_bf16(
                    a[mr], b[nc], acc[mr][nc], 0, 0, 0);
        __syncthreads();
    }

    // ---- epilogue: C/D layout col = lane&15, row = (lane>>4)*4 + reg ----
#pragma unroll
    for (int mr = 0; mr < 4; mr++) {
#pragma unroll
        for (int reg = 0; reg < 4; reg++) {
            int gr = n0 + wm * 64 + mr * 16 + kg * 4 + reg;
            if (gr >= N) continue;
#pragma unroll
            for (int nc = 0; nc < 4; nc++) {
                int gc = wn * 64 + nc * 16 + r15;
                float val = acc[mr][nc][reg] + bias[gc];
                out[(size_t)gr * CH + gc] = fmaxf(val, 0.f);
            }
        }
    }
}

extern "C" void kernel_launch(void* const* d_in, const int* in_sizes, int n_in,
                              void* d_out, int out_size, void* d_ws, size_t ws_size,
                              hipStream_t stream)
{
    const float* x    = (const float*)d_in[0];
    const int*   ei   = (const int*)d_in[1];
    const int*   et   = (const int*)d_in[2];
    const float* W    = (const float*)d_in[3];
    const float* root = (const float*)d_in[4];
    const float* bias = (const float*)d_in[5];
    float*       out  = (float*)d_out;

    int N = in_sizes[0] / CH;
    int E = in_sizes[2];
    const int* src = ei;
    const int* dst = ei + E;

    int S  = N * NREL;
    int NB = (S + SCAN_CHUNK - 1) / SCAN_CHUNK;

    // workspace layout
    unsigned short* agg = (unsigned short*)d_ws;          // N*1024 bf16 (204.8 MB)
    int* hist     = (int*)(agg + (size_t)N * KAGG);       // S
    int* offs     = hist + S;                             // S
    int* cursor   = offs + S;                             // S
    int* partials = cursor + S;                           // 256
    int* perm     = partials + 256;                       // E

    // zero hist + offs + cursor + partials in one shot (offs harmlessly included)
    hipMemsetAsync(hist, 0, ((size_t)3 * S + 256) * sizeof(int), stream);

    hist_kernel<<<1024, 256, 0, stream>>>(dst, et, hist, E);
    scan1_kernel<<<NB, SCAN_THREADS, 0, stream>>>(hist, offs, partials, S);
    scan2_kernel<<<1, SCAN_THREADS, 0, stream>>>(partials, NB);
    fill_kernel<<<1024, 256, 0, stream>>>(src, dst, et, offs, partials, cursor, perm, E);
    agg_kernel<<<(S + 3) / 4, 256, 0, stream>>>(x, perm, offs, partials, hist, agg, S);
    gemm_kernel<<<(N + BM - 1) / BM, 256, 0, stream>>>(agg, x, W, root, bias, out, N);
}

// Round 3
// 456.319 us; speedup vs baseline: 4.4269x; 1.4418x over previous
//
#include <hip/hip_runtime.h>

#define NREL 8
#define CH   128                 // IN_CH == HID == 128
#define KAGG (NREL * CH)         // 1024
#define KTOT (KAGG + CH)         // 1152

#define SCAN_ITEMS   16
#define SCAN_THREADS 256
#define SCAN_CHUNK   (SCAN_ITEMS * SCAN_THREADS)   // 4096
#define SCAN_SHIFT   12

typedef short  short8v __attribute__((ext_vector_type(8)));
typedef float  f32x4   __attribute__((ext_vector_type(4)));
typedef unsigned short u16x8 __attribute__((ext_vector_type(8)));

__device__ __forceinline__ unsigned short f2bf(float f) {
    union { float f; unsigned u; } v; v.f = f;
    return (unsigned short)((v.u + 0x7FFFu + ((v.u >> 16) & 1u)) >> 16);
}
__device__ __forceinline__ float bf2f(unsigned short h) {
    union { unsigned u; float f; } v; v.u = ((unsigned)h) << 16;
    return v.f;
}
__device__ __forceinline__ void gload_lds16(const void* g, void* l) {
    __builtin_amdgcn_global_load_lds(
        (const __attribute__((address_space(1))) unsigned int*)g,
        (__attribute__((address_space(3))) unsigned int*)l, 16, 0, 0);
}

// ---------------------------------------------------------------------------
// 0a. x fp32 -> bf16
// ---------------------------------------------------------------------------
__global__ __launch_bounds__(256) void cvtx_kernel(
    const float* __restrict__ x, unsigned short* __restrict__ xb, int total4)
{
    int i = blockIdx.x * blockDim.x + threadIdx.x;
    if (i >= total4) return;
    float4 v = *(const float4*)(x + (size_t)i * 4);
    ushort4 o;
    o.x = f2bf(v.x); o.y = f2bf(v.y); o.z = f2bf(v.z); o.w = f2bf(v.w);
    *(ushort4*)(xb + (size_t)i * 4) = o;
}

// ---------------------------------------------------------------------------
// 0b. Bt[c][k] = bf16( k<1024 ? W[k][c] : root[k-1024][c] )
// ---------------------------------------------------------------------------
__global__ __launch_bounds__(256) void bt_kernel(
    const float* __restrict__ W, const float* __restrict__ root,
    unsigned short* __restrict__ Bt)
{
    int idx = blockIdx.x * blockDim.x + threadIdx.x;   // c*1152 + k
    if (idx >= CH * KTOT) return;
    int c = idx / KTOT, k = idx - c * KTOT;
    float v = (k < KAGG) ? W[(size_t)k * CH + c] : root[(size_t)(k - KAGG) * CH + c];
    Bt[idx] = f2bf(v);
}

// ---------------------------------------------------------------------------
// 1. histogram over segments seg = dst*8 + rel
// ---------------------------------------------------------------------------
__global__ __launch_bounds__(256) void hist_kernel(
    const int* __restrict__ dst, const int* __restrict__ et,
    int* __restrict__ hist, int E)
{
    int stride = gridDim.x * blockDim.x;
    for (int e = blockIdx.x * blockDim.x + threadIdx.x; e < E; e += stride)
        atomicAdd(&hist[dst[e] * NREL + et[e]], 1);
}

// ---------------------------------------------------------------------------
// 2a/2b. two-level exclusive scan
// ---------------------------------------------------------------------------
__global__ __launch_bounds__(SCAN_THREADS) void scan1_kernel(
    const int* __restrict__ hist, int* __restrict__ offs,
    int* __restrict__ partials, int S)
{
    __shared__ int lds[SCAN_THREADS];
    int t = threadIdx.x;
    int base = blockIdx.x * SCAN_CHUNK + t * SCAN_ITEMS;
    int v[SCAN_ITEMS];
    int s = 0;
#pragma unroll
    for (int j = 0; j < SCAN_ITEMS; j++) {
        int idx = base + j;
        int h = (idx < S) ? hist[idx] : 0;
        v[j] = s; s += h;
    }
    int run = s;
    lds[t] = run; __syncthreads();
    for (int off = 1; off < SCAN_THREADS; off <<= 1) {
        int y = (t >= off) ? lds[t - off] : 0;
        __syncthreads();
        run += y; lds[t] = run; __syncthreads();
    }
    int tb = run - s;
    if (t == SCAN_THREADS - 1) partials[blockIdx.x] = run;
#pragma unroll
    for (int j = 0; j < SCAN_ITEMS; j++) {
        int idx = base + j;
        if (idx < S) offs[idx] = tb + v[j];
    }
}

__global__ __launch_bounds__(SCAN_THREADS) void scan2_kernel(
    int* __restrict__ partials, int NB)
{
    __shared__ int lds[SCAN_THREADS];
    int t = threadIdx.x;
    int s = (t < NB) ? partials[t] : 0;
    int run = s;
    lds[t] = run; __syncthreads();
    for (int off = 1; off < SCAN_THREADS; off <<= 1) {
        int y = (t >= off) ? lds[t - off] : 0;
        __syncthreads();
        run += y; lds[t] = run; __syncthreads();
    }
    if (t < NB) partials[t] = run - s;
}

// ---------------------------------------------------------------------------
// 3. fill permutation
// ---------------------------------------------------------------------------
__global__ __launch_bounds__(256) void fill_kernel(
    const int* __restrict__ src, const int* __restrict__ dst,
    const int* __restrict__ et, const int* __restrict__ offs,
    const int* __restrict__ partials, int* __restrict__ cursor,
    int* __restrict__ perm, int E)
{
    int stride = gridDim.x * blockDim.x;
    for (int e = blockIdx.x * blockDim.x + threadIdx.x; e < E; e += stride) {
        int seg = dst[e] * NREL + et[e];
        int pos = offs[seg] + partials[seg >> SCAN_SHIFT] + atomicAdd(&cursor[seg], 1);
        perm[pos] = src[e];
    }
}

// ---------------------------------------------------------------------------
// 4. segment gather-aggregate, bf16 source, 4-edge ILP.
//    wave = one segment; lane = (edge slot eg = lane>>4, channel l16 = lane&15)
//    each lane loads 8 bf16 (16 B); shfl_xor(16/32) combines the 4 edge slots.
// ---------------------------------------------------------------------------
__global__ __launch_bounds__(256) void agg_kernel(
    const unsigned short* __restrict__ xb, const int* __restrict__ perm,
    const int* __restrict__ offs, const int* __restrict__ partials,
    const int* __restrict__ hist, unsigned short* __restrict__ agg, int S)
{
    int wid  = threadIdx.x >> 6;
    int lane = threadIdx.x & 63;
    int seg  = blockIdx.x * 4 + wid;
    if (seg >= S) return;

    int beg = offs[seg] + partials[seg >> SCAN_SHIFT];
    int cnt = hist[seg];
    int eg  = lane >> 4;
    int l16 = lane & 15;

    float a[8];
#pragma unroll
    for (int j = 0; j < 8; j++) a[j] = 0.f;

    for (int e = beg + eg; e < beg + cnt; e += 4) {
        int s = perm[e];
        u16x8 v = *(const u16x8*)(xb + (size_t)s * CH + l16 * 8);
#pragma unroll
        for (int j = 0; j < 8; j++) a[j] += bf2f(v[j]);
    }
#pragma unroll
    for (int j = 0; j < 8; j++) {
        a[j] += __shfl_xor(a[j], 16);
        a[j] += __shfl_xor(a[j], 32);
    }
    if (eg == 0) {
        float inv = 1.0f / fmaxf((float)cnt, 1.0f);
        u16x8 o;
#pragma unroll
        for (int j = 0; j < 8; j++) o[j] = f2bf(a[j] * inv);
        int n = seg >> 3, r = seg & 7;
        *(u16x8*)(agg + (size_t)n * KAGG + r * CH + l16 * 8) = o;
    }
}

// ---------------------------------------------------------------------------
// 5. bf16 MFMA GEMM: out = relu([agg | xb] @ Bt^T + bias)
//    128x128 tile, BK=64, global_load_lds staging (linear LDS dest,
//    inverse-XOR-swizzled global source), swizzled ds_read_b128.
// ---------------------------------------------------------------------------
#define BM 128
#define BK 64

__global__ __launch_bounds__(256) void gemm_kernel(
    const unsigned short* __restrict__ agg,
    const unsigned short* __restrict__ xb,
    const unsigned short* __restrict__ Bt,   // [128][1152] bf16
    const float* __restrict__ bias,
    float* __restrict__ out, int N)
{
    __shared__ unsigned short As[BM * BK];   // 16 KB, swizzled content
    __shared__ unsigned short Bs[CH * BK];   // 16 KB

    int tid  = threadIdx.x;
    int n0   = blockIdx.x * BM;
    int wid  = tid >> 6;
    int lane = tid & 63;
    int wm   = wid >> 1;
    int wn   = wid & 1;
    int r15  = lane & 15;
    int kg   = lane >> 4;

    // staging geometry: chunk = 1 KB = 8 rows x (8 x 16B); lane covers
    // row_in_chunk = lane>>3, col16 = lane&7; swizzle col16 ^= row&7
    int l8   = lane >> 3;
    int c16s = (lane & 7) ^ l8;

    f32x4 acc[4][4];
#pragma unroll
    for (int i = 0; i < 4; i++)
#pragma unroll
        for (int j = 0; j < 4; j++)
            acc[i][j] = f32x4{0.f, 0.f, 0.f, 0.f};

    for (int kc = 0; kc < KTOT; kc += BK) {
        // ---- stage A (4 chunks per wave) ----
#pragma unroll
        for (int i = 0; i < 4; i++) {
            int chunk = wid * 4 + i;
            int row   = chunk * 8 + l8;
            int gn    = n0 + row;
            if (gn >= N) gn = N - 1;
            const char* srcb;
            if (kc < KAGG)
                srcb = (const char*)(agg + (size_t)gn * KAGG + kc) + c16s * 16;
            else
                srcb = (const char*)(xb + (size_t)gn * CH + (kc - KAGG)) + c16s * 16;
            gload_lds16(srcb, &As[chunk * 512]);
        }
        // ---- stage B (4 chunks per wave) ----
#pragma unroll
        for (int i = 0; i < 4; i++) {
            int chunk = wid * 4 + i;
            int c     = chunk * 8 + l8;
            const char* srcb = (const char*)(Bt + (size_t)c * KTOT + kc) + c16s * 16;
            gload_lds16(srcb, &Bs[chunk * 512]);
        }
        __syncthreads();   // drains vmcnt before any lane reads LDS

#pragma unroll
        for (int ks = 0; ks < 2; ks++) {
            short8v a[4], b[4];
#pragma unroll
            for (int mr = 0; mr < 4; mr++) {
                int row = wm * 64 + mr * 16 + r15;
                int co  = (ks * 4 + kg) ^ (row & 7);
                a[mr] = *(const short8v*)&As[row * 64 + co * 8];
            }
#pragma unroll
            for (int nc = 0; nc < 4; nc++) {
                int c  = wn * 64 + nc * 16 + r15;
                int co = (ks * 4 + kg) ^ (c & 7);
                b[nc] = *(const short8v*)&Bs[c * 64 + co * 8];
            }
#pragma unroll
            for (int mr = 0; mr < 4; mr++)
#pragma unroll
                for (int nc = 0; nc < 4; nc++)
                    acc[mr][nc] = __builtin_amdgcn_mfma_f32_16x16x32_bf16(
                        a[mr], b[nc], acc[mr][nc], 0, 0, 0);
        }
        __syncthreads();
    }

    // ---- epilogue: C/D layout col = lane&15, row = (lane>>4)*4 + reg ----
#pragma unroll
    for (int mr = 0; mr < 4; mr++) {
#pragma unroll
        for (int reg = 0; reg < 4; reg++) {
            int gr = n0 + wm * 64 + mr * 16 + kg * 4 + reg;
            if (gr >= N) continue;
#pragma unroll
            for (int nc = 0; nc < 4; nc++) {
                int gc = wn * 64 + nc * 16 + r15;
                float val = acc[mr][nc][reg] + bias[gc];
                out[(size_t)gr * CH + gc] = fmaxf(val, 0.f);
            }
        }
    }
}

extern "C" void kernel_launch(void* const* d_in, const int* in_sizes, int n_in,
                              void* d_out, int out_size, void* d_ws, size_t ws_size,
                              hipStream_t stream)
{
    const float* x    = (const float*)d_in[0];
    const int*   ei   = (const int*)d_in[1];
    const int*   et   = (const int*)d_in[2];
    const float* W    = (const float*)d_in[3];
    const float* root = (const float*)d_in[4];
    const float* bias = (const float*)d_in[5];
    float*       out  = (float*)d_out;

    int N = in_sizes[0] / CH;
    int E = in_sizes[2];
    const int* src = ei;
    const int* dst = ei + E;

    int S  = N * NREL;
    int NB = (S + SCAN_CHUNK - 1) / SCAN_CHUNK;

    // workspace layout (bf16 blocks first, then ints)
    unsigned short* agg = (unsigned short*)d_ws;              // N*1024
    unsigned short* xb  = agg + (size_t)N * KAGG;             // N*128
    unsigned short* Bt  = xb + (size_t)N * CH;                // 128*1152
    int* hist     = (int*)(Bt + (size_t)CH * KTOT);           // S
    int* offs     = hist + S;                                 // S
    int* cursor   = offs + S;                                 // S
    int* partials = cursor + S;                               // 256
    int* perm     = partials + 256;                           // E

    hipMemsetAsync(hist, 0, ((size_t)3 * S + 256) * sizeof(int), stream);

    int total4 = N * CH / 4;
    cvtx_kernel<<<(total4 + 255) / 256, 256, 0, stream>>>(x, xb, total4);
    bt_kernel<<<(CH * KTOT + 255) / 256, 256, 0, stream>>>(W, root, Bt);
    hist_kernel<<<1024, 256, 0, stream>>>(dst, et, hist, E);
    scan1_kernel<<<NB, SCAN_THREADS, 0, stream>>>(hist, offs, partials, S);
    scan2_kernel<<<1, SCAN_THREADS, 0, stream>>>(partials, NB);
    fill_kernel<<<1024, 256, 0, stream>>>(src, dst, et, offs, partials, cursor, perm, E);
    agg_kernel<<<(S + 3) / 4, 256, 0, stream>>>(xb, perm, offs, partials, hist, agg, S);
    gemm_kernel<<<(N + BM - 1) / BM, 256, 0, stream>>>(agg, xb, Bt, bias, out, N);
}

// Round 4
// 417.269 us; speedup vs baseline: 4.8412x; 1.0936x over previous
//
#include <hip/hip_runtime.h>

#define NREL 8
#define CH   128                 // IN_CH == HID == 128
#define KAGG (NREL * CH)         // 1024
#define KTOT (KAGG + CH)         // 1152

#define SCAN_ITEMS   16
#define SCAN_THREADS 256
#define SCAN_CHUNK   (SCAN_ITEMS * SCAN_THREADS)   // 4096
#define SCAN_SHIFT   12

typedef short  short8v __attribute__((ext_vector_type(8)));
typedef float  f32x4   __attribute__((ext_vector_type(4)));

__device__ __forceinline__ unsigned short f2bf(float f) {
    union { float f; unsigned u; } v; v.f = f;
    return (unsigned short)((v.u + 0x7FFFu + ((v.u >> 16) & 1u)) >> 16);
}
__device__ __forceinline__ void gload_lds16(const void* g, void* l) {
    __builtin_amdgcn_global_load_lds(
        (const __attribute__((address_space(1))) unsigned int*)g,
        (__attribute__((address_space(3))) unsigned int*)l, 16, 0, 0);
}

// ---------------------------------------------------------------------------
// 0a. x fp32 -> bf16
// ---------------------------------------------------------------------------
__global__ __launch_bounds__(256) void cvtx_kernel(
    const float* __restrict__ x, unsigned short* __restrict__ xb, int total4)
{
    int i = blockIdx.x * blockDim.x + threadIdx.x;
    if (i >= total4) return;
    float4 v = *(const float4*)(x + (size_t)i * 4);
    ushort4 o;
    o.x = f2bf(v.x); o.y = f2bf(v.y); o.z = f2bf(v.z); o.w = f2bf(v.w);
    *(ushort4*)(xb + (size_t)i * 4) = o;
}

// ---------------------------------------------------------------------------
// 0b. Bt[c][k] = bf16( k<1024 ? W[k][c] : root[k-1024][c] )
// ---------------------------------------------------------------------------
__global__ __launch_bounds__(256) void bt_kernel(
    const float* __restrict__ W, const float* __restrict__ root,
    unsigned short* __restrict__ Bt)
{
    int idx = blockIdx.x * blockDim.x + threadIdx.x;   // c*1152 + k
    if (idx >= CH * KTOT) return;
    int c = idx / KTOT, k = idx - c * KTOT;
    float v = (k < KAGG) ? W[(size_t)k * CH + c] : root[(size_t)(k - KAGG) * CH + c];
    Bt[idx] = f2bf(v);
}

// ---------------------------------------------------------------------------
// 1. histogram over segments seg = dst*8 + rel
// ---------------------------------------------------------------------------
__global__ __launch_bounds__(256) void hist_kernel(
    const int* __restrict__ dst, const int* __restrict__ et,
    int* __restrict__ hist, int E)
{
    int stride = gridDim.x * blockDim.x;
    for (int e = blockIdx.x * blockDim.x + threadIdx.x; e < E; e += stride)
        atomicAdd(&hist[dst[e] * NREL + et[e]], 1);
}

// ---------------------------------------------------------------------------
// 2a/2b. two-level exclusive scan
// ---------------------------------------------------------------------------
__global__ __launch_bounds__(SCAN_THREADS) void scan1_kernel(
    const int* __restrict__ hist, int* __restrict__ offs,
    int* __restrict__ partials, int S)
{
    __shared__ int lds[SCAN_THREADS];
    int t = threadIdx.x;
    int base = blockIdx.x * SCAN_CHUNK + t * SCAN_ITEMS;
    int v[SCAN_ITEMS];
    int s = 0;
#pragma unroll
    for (int j = 0; j < SCAN_ITEMS; j++) {
        int idx = base + j;
        int h = (idx < S) ? hist[idx] : 0;
        v[j] = s; s += h;
    }
    int run = s;
    lds[t] = run; __syncthreads();
    for (int off = 1; off < SCAN_THREADS; off <<= 1) {
        int y = (t >= off) ? lds[t - off] : 0;
        __syncthreads();
        run += y; lds[t] = run; __syncthreads();
    }
    int tb = run - s;
    if (t == SCAN_THREADS - 1) partials[blockIdx.x] = run;
#pragma unroll
    for (int j = 0; j < SCAN_ITEMS; j++) {
        int idx = base + j;
        if (idx < S) offs[idx] = tb + v[j];
    }
}

__global__ __launch_bounds__(SCAN_THREADS) void scan2_kernel(
    int* __restrict__ partials, int NB)
{
    __shared__ int lds[SCAN_THREADS];
    int t = threadIdx.x;
    int s = (t < NB) ? partials[t] : 0;
    int run = s;
    lds[t] = run; __syncthreads();
    for (int off = 1; off < SCAN_THREADS; off <<= 1) {
        int y = (t >= off) ? lds[t - off] : 0;
        __syncthreads();
        run += y; lds[t] = run; __syncthreads();
    }
    if (t < NB) partials[t] = run - s;
}

// ---------------------------------------------------------------------------
// 2c. make offs absolute; append sentinel offs[S] = E
// ---------------------------------------------------------------------------
__global__ __launch_bounds__(256) void finalize_kernel(
    int* __restrict__ offs, const int* __restrict__ partials, int S, int E)
{
    int i = blockIdx.x * blockDim.x + threadIdx.x;
    if (i < S)       offs[i] += partials[i >> SCAN_SHIFT];
    else if (i == S) offs[i] = E;
}

// ---------------------------------------------------------------------------
// 3. fill permutation (offs now absolute)
// ---------------------------------------------------------------------------
__global__ __launch_bounds__(256) void fill_kernel(
    const int* __restrict__ src, const int* __restrict__ dst,
    const int* __restrict__ et, const int* __restrict__ offs,
    int* __restrict__ cursor, int* __restrict__ perm, int E)
{
    int stride = gridDim.x * blockDim.x;
    for (int e = blockIdx.x * blockDim.x + threadIdx.x; e < E; e += stride) {
        int seg = dst[e] * NREL + et[e];
        int pos = offs[seg] + atomicAdd(&cursor[seg], 1);
        perm[pos] = src[e];
    }
}

// ---------------------------------------------------------------------------
// 4. per-NODE gather-aggregate: one wave per node, 64 lanes x 2 ch = 128 ch.
//    8 relations statically unrolled (independent reg accumulators, no
//    cross-lane reduce, epilogue amortized). Edges of a node are contiguous
//    in perm (segments n*8..n*8+7 adjacent).
// ---------------------------------------------------------------------------
__global__ __launch_bounds__(256) void agg_kernel(
    const unsigned short* __restrict__ xb, const int* __restrict__ perm,
    const int* __restrict__ offs, unsigned short* __restrict__ agg, int N)
{
    int wid  = threadIdx.x >> 6;
    int lane = threadIdx.x & 63;
    int n    = blockIdx.x * 4 + wid;
    if (n >= N) return;
    int ch = lane * 2;

    const int* op = offs + n * NREL;
    int b0 = op[0], b1 = op[1], b2 = op[2], b3 = op[3];
    int b4 = op[4], b5 = op[5], b6 = op[6], b7 = op[7], b8 = op[8];

    unsigned short* arow = agg + (size_t)n * KAGG + ch;

#define DO_REL(R, BEG, END)                                                   \
    {                                                                         \
        float alo = 0.f, ahi = 0.f;                                           \
        for (int e = (BEG); e < (END); ++e) {                                 \
            int s = perm[e];                                                  \
            unsigned v = *(const unsigned*)(xb + (size_t)s * CH + ch);        \
            union { unsigned u; float f; } flo, fhi;                          \
            flo.u = v << 16;                                                  \
            fhi.u = v & 0xFFFF0000u;                                          \
            alo += flo.f; ahi += fhi.f;                                       \
        }                                                                     \
        int c = (END) - (BEG);                                                \
        float inv = (c > 0) ? (1.0f / (float)c) : 0.f;                        \
        unsigned plo = f2bf(alo * inv);                                       \
        unsigned phi = f2bf(ahi * inv);                                       \
        *(unsigned*)(arow + (R) * CH) = plo | (phi << 16);                    \
    }

    DO_REL(0, b0, b1)
    DO_REL(1, b1, b2)
    DO_REL(2, b2, b3)
    DO_REL(3, b3, b4)
    DO_REL(4, b4, b5)
    DO_REL(5, b5, b6)
    DO_REL(6, b6, b7)
    DO_REL(7, b7, b8)
#undef DO_REL
}

// ---------------------------------------------------------------------------
// 5. bf16 MFMA GEMM: out = relu([agg | xb] @ Bt^T + bias)   (unchanged)
// ---------------------------------------------------------------------------
#define BM 128
#define BK 64

__global__ __launch_bounds__(256) void gemm_kernel(
    const unsigned short* __restrict__ agg,
    const unsigned short* __restrict__ xb,
    const unsigned short* __restrict__ Bt,   // [128][1152] bf16
    const float* __restrict__ bias,
    float* __restrict__ out, int N)
{
    __shared__ unsigned short As[BM * BK];   // 16 KB, swizzled content
    __shared__ unsigned short Bs[CH * BK];   // 16 KB

    int tid  = threadIdx.x;
    int n0   = blockIdx.x * BM;
    int wid  = tid >> 6;
    int lane = tid & 63;
    int wm   = wid >> 1;
    int wn   = wid & 1;
    int r15  = lane & 15;
    int kg   = lane >> 4;

    int l8   = lane >> 3;
    int c16s = (lane & 7) ^ l8;

    f32x4 acc[4][4];
#pragma unroll
    for (int i = 0; i < 4; i++)
#pragma unroll
        for (int j = 0; j < 4; j++)
            acc[i][j] = f32x4{0.f, 0.f, 0.f, 0.f};

    for (int kc = 0; kc < KTOT; kc += BK) {
        // ---- stage A (4 chunks per wave) ----
#pragma unroll
        for (int i = 0; i < 4; i++) {
            int chunk = wid * 4 + i;
            int row   = chunk * 8 + l8;
            int gn    = n0 + row;
            if (gn >= N) gn = N - 1;
            const char* srcb;
            if (kc < KAGG)
                srcb = (const char*)(agg + (size_t)gn * KAGG + kc) + c16s * 16;
            else
                srcb = (const char*)(xb + (size_t)gn * CH + (kc - KAGG)) + c16s * 16;
            gload_lds16(srcb, &As[chunk * 512]);
        }
        // ---- stage B (4 chunks per wave) ----
#pragma unroll
        for (int i = 0; i < 4; i++) {
            int chunk = wid * 4 + i;
            int c     = chunk * 8 + l8;
            const char* srcb = (const char*)(Bt + (size_t)c * KTOT + kc) + c16s * 16;
            gload_lds16(srcb, &Bs[chunk * 512]);
        }
        __syncthreads();

#pragma unroll
        for (int ks = 0; ks < 2; ks++) {
            short8v a[4], b[4];
#pragma unroll
            for (int mr = 0; mr < 4; mr++) {
                int row = wm * 64 + mr * 16 + r15;
                int co  = (ks * 4 + kg) ^ (row & 7);
                a[mr] = *(const short8v*)&As[row * 64 + co * 8];
            }
#pragma unroll
            for (int nc = 0; nc < 4; nc++) {
                int c  = wn * 64 + nc * 16 + r15;
                int co = (ks * 4 + kg) ^ (c & 7);
                b[nc] = *(const short8v*)&Bs[c * 64 + co * 8];
            }
#pragma unroll
            for (int mr = 0; mr < 4; mr++)
#pragma unroll
                for (int nc = 0; nc < 4; nc++)
                    acc[mr][nc] = __builtin_amdgcn_mfma_f32_16x16x32_bf16(
                        a[mr], b[nc], acc[mr][nc], 0, 0, 0);
        }
        __syncthreads();
    }

    // ---- epilogue: C/D layout col = lane&15, row = (lane>>4)*4 + reg ----
#pragma unroll
    for (int mr = 0; mr < 4; mr++) {
#pragma unroll
        for (int reg = 0; reg < 4; reg++) {
            int gr = n0 + wm * 64 + mr * 16 + kg * 4 + reg;
            if (gr >= N) continue;
#pragma unroll
            for (int nc = 0; nc < 4; nc++) {
                int gc = wn * 64 + nc * 16 + r15;
                float val = acc[mr][nc][reg] + bias[gc];
                out[(size_t)gr * CH + gc] = fmaxf(val, 0.f);
            }
        }
    }
}

extern "C" void kernel_launch(void* const* d_in, const int* in_sizes, int n_in,
                              void* d_out, int out_size, void* d_ws, size_t ws_size,
                              hipStream_t stream)
{
    const float* x    = (const float*)d_in[0];
    const int*   ei   = (const int*)d_in[1];
    const int*   et   = (const int*)d_in[2];
    const float* W    = (const float*)d_in[3];
    const float* root = (const float*)d_in[4];
    const float* bias = (const float*)d_in[5];
    float*       out  = (float*)d_out;

    int N = in_sizes[0] / CH;
    int E = in_sizes[2];
    const int* src = ei;
    const int* dst = ei + E;

    int S  = N * NREL;
    int NB = (S + SCAN_CHUNK - 1) / SCAN_CHUNK;

    // workspace layout: bf16 blocks, then ints (hist,cursor contiguous for memset)
    unsigned short* agg = (unsigned short*)d_ws;              // N*1024
    unsigned short* xb  = agg + (size_t)N * KAGG;             // N*128
    unsigned short* Bt  = xb + (size_t)N * CH;                // 128*1152
    int* hist     = (int*)(Bt + (size_t)CH * KTOT);           // S
    int* cursor   = hist + S;                                 // S
    int* offs     = cursor + S;                               // S+1
    int* partials = offs + S + 1;                             // 256
    int* perm     = partials + 256;                           // E

    hipMemsetAsync(hist, 0, (size_t)2 * S * sizeof(int), stream);

    int total4 = N * CH / 4;
    cvtx_kernel<<<(total4 + 255) / 256, 256, 0, stream>>>(x, xb, total4);
    bt_kernel<<<(CH * KTOT + 255) / 256, 256, 0, stream>>>(W, root, Bt);
    hist_kernel<<<1024, 256, 0, stream>>>(dst, et, hist, E);
    scan1_kernel<<<NB, SCAN_THREADS, 0, stream>>>(hist, offs, partials, S);
    scan2_kernel<<<1, SCAN_THREADS, 0, stream>>>(partials, NB);
    finalize_kernel<<<(S + 256) / 256, 256, 0, stream>>>(offs, partials, S, E);
    fill_kernel<<<1024, 256, 0, stream>>>(src, dst, et, offs, cursor, perm, E);
    agg_kernel<<<(N + 3) / 4, 256, 0, stream>>>(xb, perm, offs, agg, N);
    gemm_kernel<<<(N + BM - 1) / BM, 256, 0, stream>>>(agg, xb, Bt, bias, out, N);
}